// Round 2
// baseline (1387.610 us; speedup 1.0000x reference)
//
#include <hip/hip_runtime.h>

// ---------------------------------------------------------------------------
// AttentionSelfAttention: B=8, S=1024, D=64, 2NH=8 heads.
// Dtype-adaptive: a sniffer kernel detects whether tensors are stored f32 or
// bf16; all raw-input reads and final-output writes branch on the flag.
// Internals: q/k/v canonicalized to bf16 in ws, f32 accumulation.
// ws layout (bytes): [0] int flag | 1024: qws bf16[64][1024][64] | +8MB kws |
//                    +8MB vws | +8MB ctx f32[8][1024][512]   (total ~40 MB)
// ---------------------------------------------------------------------------

__device__ __forceinline__ float b2f(unsigned short u){ return __uint_as_float(((unsigned)u)<<16); }
__device__ __forceinline__ unsigned short f2b(float f){
  unsigned u = __float_as_uint(f);
  u += 0x7FFFu + ((u>>16)&1u);            // round-to-nearest-even
  return (unsigned short)(u>>16);
}
// generic element load: f32 or bf16 storage
__device__ __forceinline__ float ldf(const void* p, int i, int isf32){
  return isf32 ? ((const float*)p)[i] : b2f(((const unsigned short*)p)[i]);
}

// ---------------- kernel 0: dtype sniffer ----------------------------------
// pos_table ~ N(0, 0.02): if stored bf16, all shorts decode to |x| < 1.
// If stored f32, low-half shorts are random mantissa bits -> max >> 1.
__global__ __launch_bounds__(256) void sniff_kernel(
    const unsigned short* __restrict__ pos, int* __restrict__ flag)
{
  __shared__ float sm[256];
  const int t = threadIdx.x;
  float v = fabsf(b2f(pos[t]));
  if (!(v == v)) v = 1e30f;               // NaN -> huge (fmaxf drops NaN)
  sm[t] = v;
  __syncthreads();
  for (int o = 128; o > 0; o >>= 1){
    if (t < o) sm[t] = fmaxf(sm[t], sm[t+o]);
    __syncthreads();
  }
  if (t == 0) *flag = (sm[0] > 1.0f) ? 1 : 0;   // 1 = f32 storage
}

// ---------------- kernel 1: pos-add + 5 projections -> q/k/v (bf16) --------
__global__ __launch_bounds__(256) void proj_kernel(
    const void* __restrict__ qx, const void* __restrict__ kvx,
    const void* __restrict__ pos,
    const void* __restrict__ Wq,  const void* __restrict__ bq,
    const void* __restrict__ Wka, const void* __restrict__ bka,
    const void* __restrict__ Wva, const void* __restrict__ bva,
    const void* __restrict__ Wksa,const void* __restrict__ bksa,
    const void* __restrict__ Wvsa,const void* __restrict__ bvsa,
    unsigned short* __restrict__ qws, unsigned short* __restrict__ kws,
    unsigned short* __restrict__ vws, const int* __restrict__ flag)
{
  __shared__ float xq[64], xkv[64];
  const int isf32 = *flag;
  const int r = blockIdx.x;              // b*1024 + s
  const int s = r & 1023;
  const int t = threadIdx.x;
  if (t < 64)       xq[t] = ldf(qx, r*64 + t, isf32) + ldf(pos, s*64 + t, isf32);
  else if (t < 128) { int d = t - 64; xkv[d] = ldf(kvx, r*64 + d, isf32) + ldf(pos, s*64 + d, isf32); }
  __syncthreads();
  const int b = r >> 10;
  #pragma unroll
  for (int j = 0; j < 6; j++){
    int n = t + 256*j;                   // 0..1535 output column (branch uniform per j)
    const void *W, *bias; const float* x; unsigned short* dst; int c, h, ncol;
    if (n < 512)       { W=Wq;   bias=bq;   x=xq;  c=n;      h=c>>6;     dst=qws; ncol=512; }
    else if (n < 768)  { W=Wka;  bias=bka;  x=xkv; c=n-512;  h=c>>6;     dst=kws; ncol=256; }
    else if (n < 1024) { W=Wksa; bias=bksa; x=xq;  c=n-768;  h=4+(c>>6); dst=kws; ncol=256; }
    else if (n < 1280) { W=Wva;  bias=bva;  x=xkv; c=n-1024; h=c>>6;     dst=vws; ncol=256; }
    else               { W=Wvsa; bias=bvsa; x=xq;  c=n-1280; h=4+(c>>6); dst=vws; ncol=256; }
    float acc = ldf(bias, c, isf32);
    if (isf32){
      const float* Wf = (const float*)W;
      #pragma unroll 8
      for (int k = 0; k < 64; k++) acc += x[k] * Wf[k*ncol + c];
    } else {
      const unsigned short* Wu = (const unsigned short*)W;
      #pragma unroll 8
      for (int k = 0; k < 64; k++) acc += x[k] * b2f(Wu[k*ncol + c]);
    }
    dst[(((b<<3) + h)*1024 + s)*64 + (c & 63)] = f2b(acc);
  }
}

// ---------------- kernel 2: attention per (bh, 8-row q tile) ---------------
__global__ __launch_bounds__(256) void attn_kernel(
    const unsigned short* __restrict__ qws, const unsigned short* __restrict__ kws,
    const unsigned short* __restrict__ vws,
    void* __restrict__ d_out,                // attn at element offset 524288
    float* __restrict__ ctx,                 // [b][s][h*64+d] f32
    const int* __restrict__ flag)
{
  __shared__ float sq[8*68];
  __shared__ float stage[64*68];
  __shared__ float scT[1024*8];              // transposed scores [k][q]
  __shared__ float red[128];
  __shared__ float rowmax[8];
  __shared__ float rinv[8];

  const int isf32 = *flag;
  const int t    = threadIdx.x;
  const int qt   = blockIdx.x;               // 0..127
  const int bh   = blockIdx.y;               // 0..63
  const int q0   = qt * 8;
  const int w    = t >> 6;                   // wave id 0..3
  const int lane = t & 63;

  // load Q tile (8 x 64) into LDS
  #pragma unroll
  for (int j = 0; j < 2; j++){
    int i = t + 256*j;                       // 0..511
    int row = i >> 6, d = i & 63;
    sq[row*68 + d] = b2f(qws[((bh*1024) + q0 + row)*64 + d]);
  }

  // ---- scores: S[q][k] = (Q·K)/8, written transposed into scT ----
  for (int c = 0; c < 16; c++){
    __syncthreads();
    #pragma unroll
    for (int j = 0; j < 4; j++){             // stage K chunk rows c*64..+63
      int i4 = t + 256*j;                    // quad index 0..1023
      int row = i4 >> 4, dq = i4 & 15;
      const ushort4 u = *(const ushort4*)&kws[((bh*1024) + c*64 + row)*64 + dq*4];
      float* p = &stage[row*68 + dq*4];
      p[0]=b2f(u.x); p[1]=b2f(u.y); p[2]=b2f(u.z); p[3]=b2f(u.w);
    }
    __syncthreads();
    const int k = lane;                      // thread does scores (q=w,k) and (q=w+4,k)
    float acc0 = 0.f, acc1 = 0.f;
    #pragma unroll
    for (int d4 = 0; d4 < 16; d4++){
      float4 kv  = *(float4*)&stage[k*68 + d4*4];
      float4 qv0 = *(float4*)&sq[w*68 + d4*4];
      float4 qv1 = *(float4*)&sq[(w+4)*68 + d4*4];
      acc0 += kv.x*qv0.x + kv.y*qv0.y + kv.z*qv0.z + kv.w*qv0.w;
      acc1 += kv.x*qv1.x + kv.y*qv1.y + kv.z*qv1.z + kv.w*qv1.w;
    }
    scT[(c*64 + k)*8 + w]     = acc0 * 0.125f;
    scT[(c*64 + k)*8 + w + 4] = acc1 * 0.125f;
  }
  __syncthreads();

  // ---- softmax over k ----
  if (t < 128){
    int q = t >> 4, i = t & 15;
    float m = -1e30f;
    for (int k = i; k < 1024; k += 16) m = fmaxf(m, scT[k*8 + q]);
    red[t] = m;
  }
  __syncthreads();
  if (t < 8){
    float m = red[t*16];
    #pragma unroll
    for (int i = 1; i < 16; i++) m = fmaxf(m, red[t*16 + i]);
    rowmax[t] = m;
  }
  __syncthreads();
  if (t < 128){
    int q = t >> 4, i = t & 15;
    float m = rowmax[q], ssum = 0.f;
    for (int k = i; k < 1024; k += 16){
      float p = __expf(scT[k*8 + q] - m);
      scT[k*8 + q] = p;
      ssum += p;
    }
    red[t] = ssum;
  }
  __syncthreads();
  if (t < 8){
    float ssum = 0.f;
    #pragma unroll
    for (int i = 0; i < 16; i++) ssum += red[t*16 + i];
    rinv[t] = 1.f / ssum;
  }
  __syncthreads();

  // ---- normalize, write attn (dtype-adaptive), keep normalized p in scT ----
  {
    const int base = (bh*1024 + q0) * 1024;
    #pragma unroll
    for (int j = 0; j < 8; j++){
      int i4 = t + 256*j;                    // 0..2047 quads (8192 elems)
      int q  = i4 >> 8;
      int k0 = (i4 & 255) * 4;
      float ri = rinv[q];
      float p0 = scT[(k0+0)*8+q] * ri;
      float p1 = scT[(k0+1)*8+q] * ri;
      float p2 = scT[(k0+2)*8+q] * ri;
      float p3 = scT[(k0+3)*8+q] * ri;
      scT[(k0+0)*8+q]=p0; scT[(k0+1)*8+q]=p1; scT[(k0+2)*8+q]=p2; scT[(k0+3)*8+q]=p3;
      if (isf32){
        float* ao = (float*)d_out + 524288;
        float4 f; f.x=p0; f.y=p1; f.z=p2; f.w=p3;
        *(float4*)&ao[base + q*1024 + k0] = f;
      } else {
        unsigned short* ao = (unsigned short*)d_out + 524288;
        ushort4 u; u.x=f2b(p0); u.y=f2b(p1); u.z=f2b(p2); u.w=f2b(p3);
        *(ushort4*)&ao[base + q*1024 + k0] = u;
      }
    }
  }

  // ---- ctx[q][d] = sum_k p[q][k] * V[k][d]; waves split k ----
  float acc[8];
  #pragma unroll
  for (int qi = 0; qi < 8; qi++) acc[qi] = 0.f;
  const int d = lane;
  for (int c = 0; c < 16; c++){
    __syncthreads();
    #pragma unroll
    for (int j = 0; j < 4; j++){             // stage V chunk
      int i4 = t + 256*j;
      int row = i4 >> 4, dq = i4 & 15;
      const ushort4 u = *(const ushort4*)&vws[((bh*1024) + c*64 + row)*64 + dq*4];
      float* p = &stage[row*68 + dq*4];
      p[0]=b2f(u.x); p[1]=b2f(u.y); p[2]=b2f(u.z); p[3]=b2f(u.w);
    }
    __syncthreads();
    for (int kk = w*16; kk < w*16 + 16; kk++){  // wave-uniform k
      int kg = c*64 + kk;
      float4 pa = *(float4*)&scT[kg*8];
      float4 pb = *(float4*)&scT[kg*8 + 4];
      float v = stage[kk*68 + d];
      acc[0] += pa.x*v; acc[1] += pa.y*v; acc[2] += pa.z*v; acc[3] += pa.w*v;
      acc[4] += pb.x*v; acc[5] += pb.y*v; acc[6] += pb.z*v; acc[7] += pb.w*v;
    }
  }
  __syncthreads();
  float* pbuf = stage;                       // reuse: [w][q][d] = 4*8*64 floats
  #pragma unroll
  for (int qi = 0; qi < 8; qi++) pbuf[(w*8 + qi)*64 + d] = acc[qi];
  __syncthreads();
  {
    const int b = bh >> 3, h = bh & 7;
    #pragma unroll
    for (int j = 0; j < 2; j++){
      int o = t + 256*j;                     // 0..511
      int q = o >> 6, dd = o & 63;
      float v = pbuf[(0*8+q)*64+dd] + pbuf[(1*8+q)*64+dd]
              + pbuf[(2*8+q)*64+dd] + pbuf[(3*8+q)*64+dd];
      ctx[(b*1024 + q0 + q)*512 + h*64 + dd] = v;
    }
  }
}

// ---------------- kernel 3: out = ctx @ Wo + bo ----------------------------
__global__ __launch_bounds__(256) void outproj_kernel(
    const float* __restrict__ ctx, const void* __restrict__ Wo,
    const void* __restrict__ bo, void* __restrict__ d_out,
    const int* __restrict__ flag)
{
  __shared__ float sctx[4*512];
  const int isf32 = *flag;
  const int t  = threadIdx.x;
  const int r0 = blockIdx.x * 4;
  #pragma unroll
  for (int j = 0; j < 8; j++){
    int i = t + 256*j;                       // 0..2047
    sctx[i] = ctx[r0*512 + i];
  }
  __syncthreads();
  const int row = t >> 6, dc = t & 63;
  float acc = ldf(bo, dc, isf32);
  if (isf32){
    const float* Wf = (const float*)Wo;
    #pragma unroll 8
    for (int c = 0; c < 512; c++) acc += sctx[row*512 + c] * Wf[c*64 + dc];
    ((float*)d_out)[(r0 + row)*64 + dc] = acc;
  } else {
    const unsigned short* Wu = (const unsigned short*)Wo;
    #pragma unroll 8
    for (int c = 0; c < 512; c++) acc += sctx[row*512 + c] * b2f(Wu[c*64 + dc]);
    ((unsigned short*)d_out)[(r0 + row)*64 + dc] = f2b(acc);
  }
}

// ---------------------------------------------------------------------------
extern "C" void kernel_launch(void* const* d_in, const int* in_sizes, int n_in,
                              void* d_out, int out_size, void* d_ws, size_t ws_size,
                              hipStream_t stream)
{
  const void* kvx  = d_in[0];
  const void* qx   = d_in[1];
  const void* pos  = d_in[2];
  const void* Wq   = d_in[3];
  const void* bq   = d_in[4];
  const void* Wka  = d_in[5];
  const void* bka  = d_in[6];
  const void* Wva  = d_in[7];
  const void* bva  = d_in[8];
  const void* Wksa = d_in[9];
  const void* bksa = d_in[10];
  const void* Wvsa = d_in[11];
  const void* bvsa = d_in[12];
  const void* Wo   = d_in[13];
  const void* bo   = d_in[14];

  int* flag           = (int*)d_ws;
  unsigned short* qws = (unsigned short*)((char*)d_ws + 1024);
  unsigned short* kws = qws + 4194304;       // 64 x 1024 x 64 bf16 each
  unsigned short* vws = kws + 4194304;
  float*          ctx = (float*)(vws + 4194304);   // 8 x 1024 x 512 f32

  sniff_kernel<<<dim3(1), dim3(256), 0, stream>>>((const unsigned short*)pos, flag);
  proj_kernel<<<dim3(8192), dim3(256), 0, stream>>>(
      qx, kvx, pos, Wq, bq, Wka, bka, Wva, bva, Wksa, bksa, Wvsa, bvsa,
      qws, kws, vws, flag);
  attn_kernel<<<dim3(128, 64), dim3(256), 0, stream>>>(qws, kws, vws, d_out, ctx, flag);
  outproj_kernel<<<dim3(2048), dim3(256), 0, stream>>>(ctx, Wo, bo, d_out, flag);
}

// Round 3
// 560.172 us; speedup vs baseline: 2.4771x; 2.4771x over previous
//
#include <hip/hip_runtime.h>

// ---------------------------------------------------------------------------
// AttentionSelfAttention: B=8, S=1024, D=64, 2NH=8 heads. bf16 I/O (sniffed),
// f32 accumulation. Round 3: MFMA flash-style attention (two-pass softmax).
// ws: [0] flag | qws bf16[64][1024][64] | kws bf16[64][1024][64] |
//     vtws bf16[64][64][1024] (V transposed!) | ctx f32[8][1024][512]
// ---------------------------------------------------------------------------

typedef unsigned short u16;
typedef __attribute__((ext_vector_type(8))) short bf16x8;
typedef __attribute__((ext_vector_type(4))) float f32x4;
#define MFMA16(a,b,c) __builtin_amdgcn_mfma_f32_16x16x32_bf16(a,b,c,0,0,0)

__device__ __forceinline__ float b2f(u16 u){ return __uint_as_float(((unsigned)u)<<16); }
__device__ __forceinline__ u16 f2b(float f){
  unsigned u = __float_as_uint(f);
  u += 0x7FFFu + ((u>>16)&1u);
  return (u16)(u>>16);
}
__device__ __forceinline__ float ldf(const void* p, int i, int isf32){
  return isf32 ? ((const float*)p)[i] : b2f(((const u16*)p)[i]);
}

// ---------------- kernel 0: dtype sniffer ----------------------------------
__global__ __launch_bounds__(256) void sniff_kernel(
    const u16* __restrict__ pos, int* __restrict__ flag)
{
  __shared__ float sm[256];
  const int t = threadIdx.x;
  float v = fabsf(b2f(pos[t]));
  if (!(v == v)) v = 1e30f;
  sm[t] = v;
  __syncthreads();
  for (int o = 128; o > 0; o >>= 1){
    if (t < o) sm[t] = fmaxf(sm[t], sm[t+o]);
    __syncthreads();
  }
  if (t == 0) *flag = (sm[0] > 1.0f) ? 1 : 0;   // 1 = f32 storage
}

// ---------------- kernel 1: pos-add + 5 projections ------------------------
// qws/kws: [bh][s][64] row-major.  vtws: [bh][d][s] TRANSPOSED for attn B-frags.
__global__ __launch_bounds__(256) void proj_kernel(
    const void* __restrict__ qx, const void* __restrict__ kvx,
    const void* __restrict__ pos,
    const void* __restrict__ Wq,  const void* __restrict__ bq,
    const void* __restrict__ Wka, const void* __restrict__ bka,
    const void* __restrict__ Wva, const void* __restrict__ bva,
    const void* __restrict__ Wksa,const void* __restrict__ bksa,
    const void* __restrict__ Wvsa,const void* __restrict__ bvsa,
    u16* __restrict__ qws, u16* __restrict__ kws,
    u16* __restrict__ vtws, const int* __restrict__ flag)
{
  __shared__ float xq[64], xkv[64];
  const int isf32 = *flag;
  const int r = blockIdx.x;              // b*1024 + s
  const int s = r & 1023;
  const int t = threadIdx.x;
  if (t < 64)       xq[t] = ldf(qx, r*64 + t, isf32) + ldf(pos, s*64 + t, isf32);
  else if (t < 128) { int d = t - 64; xkv[d] = ldf(kvx, r*64 + d, isf32) + ldf(pos, s*64 + d, isf32); }
  __syncthreads();
  const int b = r >> 10;
  #pragma unroll
  for (int j = 0; j < 6; j++){
    int n = t + 256*j;                   // 0..1535
    const void *W, *bias; const float* x; int c, h, ncol, isv;
    if (n < 512)       { W=Wq;   bias=bq;   x=xq;  c=n;      h=c>>6;     ncol=512; isv=0; }
    else if (n < 768)  { W=Wka;  bias=bka;  x=xkv; c=n-512;  h=c>>6;     ncol=256; isv=0; }
    else if (n < 1024) { W=Wksa; bias=bksa; x=xq;  c=n-768;  h=4+(c>>6); ncol=256; isv=0; }
    else if (n < 1280) { W=Wva;  bias=bva;  x=xkv; c=n-1024; h=c>>6;     ncol=256; isv=1; }
    else               { W=Wvsa; bias=bvsa; x=xq;  c=n-1280; h=4+(c>>6); ncol=256; isv=1; }
    float acc = ldf(bias, c, isf32);
    if (isf32){
      const float* Wf = (const float*)W;
      #pragma unroll 8
      for (int k = 0; k < 64; k++) acc += x[k] * Wf[k*ncol + c];
    } else {
      const u16* Wu = (const u16*)W;
      #pragma unroll 8
      for (int k = 0; k < 64; k++) acc += x[k] * b2f(Wu[k*ncol + c]);
    }
    const int bh = (b<<3) + h, d = c & 63;
    u16 val = f2b(acc);
    if (n < 512)      qws[(bh*1024 + s)*64 + d] = val;
    else if (!isv)    kws[(bh*1024 + s)*64 + d] = val;
    else              vtws[(bh*64 + d)*1024 + s] = val;
  }
}

// ---------------- kernel 2: MFMA flash attention ---------------------------
// Block: 64 q-rows of one bh; 4 waves x 16 q-rows. Chunks of 64 k.
__global__ __launch_bounds__(256) void attn_kernel(
    const u16* __restrict__ qws, const u16* __restrict__ kws,
    const u16* __restrict__ vtws,
    void* __restrict__ d_out, float* __restrict__ ctx,
    const int* __restrict__ flag)
{
  __shared__ u16 sK [64*72];      // [k][d], stride 72 (144B rows -> 2-way max)
  __shared__ u16 sVT[64*72];      // [d][k]
  __shared__ u16 sP [4][16*72];   // per-wave [q][k]

  const int isf32 = *flag;
  const int t    = threadIdx.x;
  const int w    = t >> 6;
  const int lane = t & 63;
  const int L15  = lane & 15;
  const int quad = lane >> 4;
  const int bh   = blockIdx.y;
  const int q0   = blockIdx.x * 64;
  const int qw   = q0 + w*16;

  const u16* kg = kws  + bh*1024*64;
  const u16* vg = vtws + bh*64*1024;

  // Q A-frags: A[m=L15][k-dim d = quad*8+j], persist in regs
  const u16* qbase = qws + (bh*1024 + qw + L15)*64;
  const bf16x8 aq0 = *(const bf16x8*)(qbase + quad*8);
  const bf16x8 aq1 = *(const bf16x8*)(qbase + 32 + quad*8);

  float m_run[4] = {-1e30f,-1e30f,-1e30f,-1e30f};
  float l_run[4] = {0.f,0.f,0.f,0.f};

  const int srow = t >> 2;            // staging: 0..63
  const int scol = (t & 3) * 16;      // 0/16/32/48

  // ---------------- pass 1: row max & sum ----------------
  for (int c = 0; c < 16; c++){
    __syncthreads();
    { const uint4* src = (const uint4*)(kg + (c*64 + srow)*64 + scol);
      uint4* dst = (uint4*)(sK + srow*72 + scol);
      dst[0] = src[0]; dst[1] = src[1]; }
    __syncthreads();
    f32x4 acc[4] = {};
    #pragma unroll
    for (int tt = 0; tt < 4; tt++){
      bf16x8 b0 = *(const bf16x8*)(sK + (tt*16 + L15)*72 + quad*8);
      bf16x8 b1 = *(const bf16x8*)(sK + (tt*16 + L15)*72 + 32 + quad*8);
      acc[tt] = MFMA16(aq0, b0, acc[tt]);
      acc[tt] = MFMA16(aq1, b1, acc[tt]);
    }
    #pragma unroll
    for (int r = 0; r < 4; r++){
      float v0 = acc[0][r]*0.125f, v1 = acc[1][r]*0.125f;
      float v2 = acc[2][r]*0.125f, v3 = acc[3][r]*0.125f;
      float cmax = fmaxf(fmaxf(v0,v1), fmaxf(v2,v3));
      cmax = fmaxf(cmax, __shfl_xor(cmax, 1));
      cmax = fmaxf(cmax, __shfl_xor(cmax, 2));
      cmax = fmaxf(cmax, __shfl_xor(cmax, 4));
      cmax = fmaxf(cmax, __shfl_xor(cmax, 8));
      float mnew = fmaxf(m_run[r], cmax);
      float cs = __expf(v0-mnew) + __expf(v1-mnew) + __expf(v2-mnew) + __expf(v3-mnew);
      cs += __shfl_xor(cs, 1);
      cs += __shfl_xor(cs, 2);
      cs += __shfl_xor(cs, 4);
      cs += __shfl_xor(cs, 8);
      l_run[r] = l_run[r]*__expf(m_run[r]-mnew) + cs;
      m_run[r] = mnew;
    }
  }

  float linv[4];
  #pragma unroll
  for (int r = 0; r < 4; r++) linv[r] = 1.f / l_run[r];

  // ---------------- pass 2: attn write + PV ----------------
  f32x4 octx[4] = {};
  u16* sPw = sP[w];
  for (int c = 0; c < 16; c++){
    __syncthreads();
    { const uint4* srcK = (const uint4*)(kg + (c*64 + srow)*64 + scol);
      uint4* dstK = (uint4*)(sK + srow*72 + scol);
      dstK[0] = srcK[0]; dstK[1] = srcK[1];
      const uint4* srcV = (const uint4*)(vg + srow*1024 + c*64 + scol);
      uint4* dstV = (uint4*)(sVT + srow*72 + scol);
      dstV[0] = srcV[0]; dstV[1] = srcV[1]; }
    __syncthreads();
    // recompute scores, normalize, deposit P into per-wave LDS tile
    #pragma unroll
    for (int tt = 0; tt < 4; tt++){
      bf16x8 b0 = *(const bf16x8*)(sK + (tt*16 + L15)*72 + quad*8);
      bf16x8 b1 = *(const bf16x8*)(sK + (tt*16 + L15)*72 + 32 + quad*8);
      f32x4 acc = {};
      acc = MFMA16(aq0, b0, acc);
      acc = MFMA16(aq1, b1, acc);
      #pragma unroll
      for (int r = 0; r < 4; r++){
        float p = __expf(acc[r]*0.125f - m_run[r]) * linv[r];
        sPw[(quad*4 + r)*72 + tt*16 + L15] = f2b(p);
      }
    }
    // coalesced attn write from sP (wave-local; in-wave lgkm ordering)
    { int row = lane >> 2, cc = (lane & 3) * 16;
      const uint4* ps = (const uint4*)(sPw + row*72 + cc);
      uint4 u0 = ps[0], u1 = ps[1];
      long gofs = ((long)(bh*1024 + qw + row))*1024 + c*64 + cc;
      if (isf32){
        float* ao = (float*)d_out + 524288 + gofs;
        const u16* h0 = (const u16*)&u0; const u16* h1 = (const u16*)&u1;
        float4 f0, f1, f2, f3;
        f0.x=b2f(h0[0]); f0.y=b2f(h0[1]); f0.z=b2f(h0[2]); f0.w=b2f(h0[3]);
        f1.x=b2f(h0[4]); f1.y=b2f(h0[5]); f1.z=b2f(h0[6]); f1.w=b2f(h0[7]);
        f2.x=b2f(h1[0]); f2.y=b2f(h1[1]); f2.z=b2f(h1[2]); f2.w=b2f(h1[3]);
        f3.x=b2f(h1[4]); f3.y=b2f(h1[5]); f3.z=b2f(h1[6]); f3.w=b2f(h1[7]);
        *(float4*)(ao+0) = f0; *(float4*)(ao+4) = f1;
        *(float4*)(ao+8) = f2; *(float4*)(ao+12) = f3;
      } else {
        uint4* gd = (uint4*)((u16*)d_out + 524288 + gofs);
        gd[0] = u0; gd[1] = u1;
      }
    }
    // PV: A = P [q][k], B = V [k][d] (from transposed sVT[d][k])
    #pragma unroll
    for (int s = 0; s < 2; s++){
      bf16x8 ap = *(const bf16x8*)(sPw + L15*72 + s*32 + quad*8);
      #pragma unroll
      for (int tt = 0; tt < 4; tt++){
        bf16x8 bv = *(const bf16x8*)(sVT + (tt*16 + L15)*72 + s*32 + quad*8);
        octx[tt] = MFMA16(ap, bv, octx[tt]);
      }
    }
  }

  // write ctx f32 [b][s][h*64+d]
  const int b = bh >> 3, h = bh & 7;
  #pragma unroll
  for (int tt = 0; tt < 4; tt++)
    #pragma unroll
    for (int r = 0; r < 4; r++)
      ctx[(b*1024 + qw + quad*4 + r)*512 + h*64 + tt*16 + L15] = octx[tt][r];
}

// ---------------- kernel 3: out = ctx @ Wo + bo ----------------------------
__global__ __launch_bounds__(256) void outproj_kernel(
    const float* __restrict__ ctx, const void* __restrict__ Wo,
    const void* __restrict__ bo, void* __restrict__ d_out,
    const int* __restrict__ flag)
{
  __shared__ float sctx[4*512];
  const int isf32 = *flag;
  const int t  = threadIdx.x;
  const int r0 = blockIdx.x * 4;
  #pragma unroll
  for (int j = 0; j < 8; j++){
    int i = t + 256*j;
    sctx[i] = ctx[r0*512 + i];
  }
  __syncthreads();
  const int row = t >> 6, dc = t & 63;
  float acc = ldf(bo, dc, isf32);
  if (isf32){
    const float* Wf = (const float*)Wo;
    #pragma unroll 8
    for (int c = 0; c < 512; c++) acc += sctx[row*512 + c] * Wf[c*64 + dc];
    ((float*)d_out)[(r0 + row)*64 + dc] = acc;
  } else {
    const u16* Wu = (const u16*)Wo;
    #pragma unroll 8
    for (int c = 0; c < 512; c++) acc += sctx[row*512 + c] * b2f(Wu[c*64 + dc]);
    ((u16*)d_out)[(r0 + row)*64 + dc] = f2b(acc);
  }
}

// ---------------------------------------------------------------------------
extern "C" void kernel_launch(void* const* d_in, const int* in_sizes, int n_in,
                              void* d_out, int out_size, void* d_ws, size_t ws_size,
                              hipStream_t stream)
{
  const void* kvx  = d_in[0];
  const void* qx   = d_in[1];
  const void* pos  = d_in[2];
  const void* Wq   = d_in[3];
  const void* bq   = d_in[4];
  const void* Wka  = d_in[5];
  const void* bka  = d_in[6];
  const void* Wva  = d_in[7];
  const void* bva  = d_in[8];
  const void* Wksa = d_in[9];
  const void* bksa = d_in[10];
  const void* Wvsa = d_in[11];
  const void* bvsa = d_in[12];
  const void* Wo   = d_in[13];
  const void* bo   = d_in[14];

  int* flag = (int*)d_ws;
  u16* qws  = (u16*)((char*)d_ws + 1024);
  u16* kws  = qws + 4194304;
  u16* vtws = kws + 4194304;            // transposed [bh][d][s]
  float* ctx = (float*)(vtws + 4194304);

  sniff_kernel<<<dim3(1), dim3(256), 0, stream>>>((const u16*)pos, flag);
  proj_kernel<<<dim3(8192), dim3(256), 0, stream>>>(
      qx, kvx, pos, Wq, bq, Wka, bka, Wva, bva, Wksa, bksa, Wvsa, bvsa,
      qws, kws, vtws, flag);
  attn_kernel<<<dim3(16, 64), dim3(256), 0, stream>>>(qws, kws, vtws, d_out, ctx, flag);
  outproj_kernel<<<dim3(2048), dim3(256), 0, stream>>>(ctx, Wo, bo, d_out, flag);
}